// Round 1
// baseline (52.410 us; speedup 1.0000x reference)
//
#include <hip/hip_runtime.h>
#include <math.h>

// Problem constants (fixed by reference): N=512, IN_F=128, OUT_F=64, H=4.
// e_raw[i,j,h] = s1[i][j>>7][h] + s2[j][h]
//   s1[i][g][h] = sum_f ht[i][g*64+f] * a[h][f]
//   s2[j][h]    = sum_f ht[j][h*64+f] * a[h][64+f]
// then leaky_relu(0.2), * ew[i][j], mask adj, softmax over j,
// c[i][h*64+f] = sum_j alpha * ht[j][h*64+f], out = sigmoid(h U^T + c V^T).

__device__ __forceinline__ float wave_sum(float v) {
    #pragma unroll
    for (int o = 32; o; o >>= 1) v += __shfl_xor(v, o, 64);
    return v;
}
__device__ __forceinline__ float wave_max(float v) {
    #pragma unroll
    for (int o = 32; o; o >>= 1) v = fmaxf(v, __shfl_xor(v, o, 64));
    return v;
}

// ---------------- K1: ht = h @ W^T, plus s1, s2 ----------------
// grid 128 blocks x 256 thr, 4 rows per block. col = threadIdx.x.
__global__ __launch_bounds__(256) void k_transform(
    const float* __restrict__ h, const float* __restrict__ W,
    const float* __restrict__ a,
    float* __restrict__ ht, float* __restrict__ s1, float* __restrict__ s2p)
{
    __shared__ float hsh[4 * 128];
    __shared__ float ash[512];   // a[4][128]
    const int t = threadIdx.x;
    const int i0 = blockIdx.x * 4;
    if (t < 128) ((float4*)hsh)[t] = ((const float4*)(h + i0 * 128))[t];
    else         ((float4*)ash)[t - 128] = ((const float4*)a)[t - 128];
    __syncthreads();

    float acc[4] = {0.f, 0.f, 0.f, 0.f};
    const float4* Wv = (const float4*)(W + t * 128);
    #pragma unroll
    for (int kk = 0; kk < 32; ++kk) {
        float4 w4 = Wv[kk];
        #pragma unroll
        for (int r = 0; r < 4; ++r) {
            const float* hp = hsh + r * 128 + kk * 4;
            acc[r] += w4.x * hp[0] + w4.y * hp[1] + w4.z * hp[2] + w4.w * hp[3];
        }
    }
    const int w = t >> 6, lane = t & 63;   // w = g (column block) = head idx for s2
    #pragma unroll
    for (int r = 0; r < 4; ++r) {
        ht[(i0 + r) * 256 + t] = acc[r];
        #pragma unroll
        for (int h2 = 0; h2 < 4; ++h2) {
            float p = wave_sum(acc[r] * ash[h2 * 128 + lane]);   // a[h2][f], f=lane
            if (lane == 0) s1[(i0 + r) * 16 + w * 4 + h2] = p;
        }
        float p2 = wave_sum(acc[r] * ash[w * 128 + 64 + lane]);  // a[w][64+f]
        if (lane == 0) s2p[w * 512 + (i0 + r)] = p2;             // s2 planes [h][j]
    }
}

// ---------------- K2: attention + aggregate ----------------
// grid 256 blocks (64 i-tiles x 4 heads) x 256 thr. 8 rows per block.
__global__ __launch_bounds__(256) void k_att(
    const int* __restrict__ adj, const float* __restrict__ ew,
    const float* __restrict__ ht, const float* __restrict__ s1,
    const float* __restrict__ s2p, float* __restrict__ c)
{
    __shared__ float att[8 * 512];   // 16 KB
    __shared__ float s1sh[8 * 4];
    __shared__ float s2sh[512];
    const int t = threadIdx.x;
    const int hh = blockIdx.x & 3;
    const int i0 = (blockIdx.x >> 2) * 8;

    s2sh[t]       = s2p[hh * 512 + t];
    s2sh[t + 256] = s2p[hh * 512 + 256 + t];
    if (t < 32) s1sh[t] = s1[(i0 + (t >> 2)) * 16 + (t & 3) * 4 + hh];
    __syncthreads();

    // masked, weighted scores
    #pragma unroll
    for (int pass = 0; pass < 16; ++pass) {
        int idx = pass * 256 + t;
        int r = idx >> 9, j = idx & 511;
        float e = s1sh[r * 4 + (j >> 7)] + s2sh[j];
        e = (e >= 0.f) ? e : 0.2f * e;                  // leaky_relu(0.2)
        e *= ew[(i0 + r) * 512 + j];
        att[idx] = (adj[(i0 + r) * 512 + j] > 0) ? e : -9.0e15f;
    }
    __syncthreads();

    // per-row softmax (wave w handles rows w and w+4)
    const int w = t >> 6, lane = t & 63;
    #pragma unroll
    for (int rr = w; rr < 8; rr += 4) {
        float m = -INFINITY;
        for (int j = lane; j < 512; j += 64) m = fmaxf(m, att[rr * 512 + j]);
        m = wave_max(m);
        float s = 0.f;
        for (int j = lane; j < 512; j += 64) s += __expf(att[rr * 512 + j] - m);
        s = wave_sum(s);
        float inv = 1.f / s;
        for (int j = lane; j < 512; j += 64)
            att[rr * 512 + j] = __expf(att[rr * 512 + j] - m) * inv;
    }
    __syncthreads();

    // c[i][hh*64+f] = sum_j alpha[j] * ht[j][hh*64+f]; wave w does rows w, w+4
    float acc0 = 0.f, acc1 = 0.f;
    const float* htp = ht + hh * 64 + lane;
    #pragma unroll 8
    for (int j = 0; j < 512; ++j) {
        float htv = htp[j * 256];
        acc0 += att[w * 512 + j] * htv;
        acc1 += att[(w + 4) * 512 + j] * htv;
    }
    c[(i0 + w)     * 256 + hh * 64 + lane] = acc0;
    c[(i0 + w + 4) * 256 + hh * 64 + lane] = acc1;
}

// ---------------- K3: out = sigmoid(h U^T + c V^T) ----------------
// grid 128 blocks x 256 thr, 4 rows per block. col = threadIdx.x.
__global__ __launch_bounds__(256) void k_out(
    const float* __restrict__ h, const float* __restrict__ cbuf,
    const float* __restrict__ U, const float* __restrict__ V,
    float* __restrict__ out)
{
    __shared__ float hsh[4 * 128];
    __shared__ float csh[4 * 256];
    const int t = threadIdx.x;
    const int i0 = blockIdx.x * 4;
    if (t < 128) ((float4*)hsh)[t] = ((const float4*)(h + i0 * 128))[t];
    ((float4*)csh)[t] = ((const float4*)(cbuf + i0 * 256))[t];
    __syncthreads();

    float acc[4] = {0.f, 0.f, 0.f, 0.f};
    const float4* Uv = (const float4*)(U + t * 128);
    #pragma unroll
    for (int kk = 0; kk < 32; ++kk) {
        float4 u4 = Uv[kk];
        #pragma unroll
        for (int r = 0; r < 4; ++r) {
            const float* hp = hsh + r * 128 + kk * 4;
            acc[r] += u4.x * hp[0] + u4.y * hp[1] + u4.z * hp[2] + u4.w * hp[3];
        }
    }
    const float4* Vv = (const float4*)(V + t * 256);
    #pragma unroll
    for (int kk = 0; kk < 64; ++kk) {
        float4 v4 = Vv[kk];
        #pragma unroll
        for (int r = 0; r < 4; ++r) {
            const float* cp = csh + r * 256 + kk * 4;
            acc[r] += v4.x * cp[0] + v4.y * cp[1] + v4.z * cp[2] + v4.w * cp[3];
        }
    }
    #pragma unroll
    for (int r = 0; r < 4; ++r)
        out[(i0 + r) * 256 + t] = 1.f / (1.f + __expf(-acc[r]));
}

extern "C" void kernel_launch(void* const* d_in, const int* in_sizes, int n_in,
                              void* d_out, int out_size, void* d_ws, size_t ws_size,
                              hipStream_t stream) {
    const float* h   = (const float*)d_in[0];
    const int*   adj = (const int*)d_in[1];
    const float* ew  = (const float*)d_in[2];
    const float* W   = (const float*)d_in[3];
    const float* a   = (const float*)d_in[4];
    const float* U   = (const float*)d_in[5];
    const float* V   = (const float*)d_in[6];
    float* out = (float*)d_out;

    float* ht  = (float*)d_ws;           // 512*256
    float* s1  = ht + 512 * 256;         // 512*16
    float* s2p = s1 + 512 * 16;          // 4*512
    float* c   = s2p + 4 * 512;          // 512*256

    k_transform<<<128, 256, 0, stream>>>(h, W, a, ht, s1, s2p);
    k_att<<<256, 256, 0, stream>>>(adj, ew, ht, s1, s2p, c);
    k_out<<<128, 256, 0, stream>>>(h, c, U, V, out);
}

// Round 2
// 32.800 us; speedup vs baseline: 1.5979x; 1.5979x over previous
//
#include <hip/hip_runtime.h>
#include <math.h>

// N=512, IN_F=128, OUT_F=64, H=4.
// e_raw[i,j,h] = s1[i][j>>7][h] + s2[j][h]
//   s1[i][g][h] = dot(ht[i][g*64:], a[h][:64]) ; s2[j][h] = dot(ht[j][h*64:], a[h][64:])
// leaky_relu(0.2) -> *ew -> mask adj -> softmax over j
// c[i][h*64+f] = sum_j alpha[i,j,h]*ht[j][h*64+f] ; out = sigmoid(h U^T + c V^T)

__device__ __forceinline__ float wave_sum(float v) {
    #pragma unroll
    for (int o = 32; o; o >>= 1) v += __shfl_xor(v, o, 64);
    return v;
}
__device__ __forceinline__ float wave_max(float v) {
    #pragma unroll
    for (int o = 32; o; o >>= 1) v = fmaxf(v, __shfl_xor(v, o, 64));
    return v;
}

// ---------------- K1: ht = h @ W^T, plus s1, s2 ----------------
// 256 blocks x 256 thr, 2 rows/block.
__global__ __launch_bounds__(256) void k_transform(
    const float* __restrict__ h, const float* __restrict__ W,
    const float* __restrict__ a,
    float* __restrict__ ht, float* __restrict__ s1, float* __restrict__ s2p)
{
    __shared__ float hsh[2 * 128];
    __shared__ float ash[512];      // a[4][128]
    __shared__ float hts[2 * 256];  // this block's ht rows
    const int t = threadIdx.x;
    const int i0 = blockIdx.x * 2;
    if (t < 64)       ((float4*)hsh)[t]      = ((const float4*)(h + i0 * 128))[t];
    else if (t < 192) ((float4*)ash)[t - 64] = ((const float4*)a)[t - 64];
    __syncthreads();

    float acc0 = 0.f, acc1 = 0.f;
    const float4* Wv = (const float4*)(W + t * 128);
    #pragma unroll
    for (int kk = 0; kk < 32; ++kk) {
        float4 w4 = Wv[kk];
        const float* h0 = hsh + kk * 4;
        const float* h1 = hsh + 128 + kk * 4;
        acc0 += w4.x * h0[0] + w4.y * h0[1] + w4.z * h0[2] + w4.w * h0[3];
        acc1 += w4.x * h1[0] + w4.y * h1[1] + w4.z * h1[2] + w4.w * h1[3];
    }
    ht[i0 * 256 + t]       = acc0;
    ht[(i0 + 1) * 256 + t] = acc1;
    hts[t]       = acc0;
    hts[256 + t] = acc1;
    __syncthreads();

    // 40 small dots replace 20 shuffle butterflies: t<40, r=t&1, o=t>>1
    if (t < 40) {
        const int r = t & 1, o = t >> 1;
        const float* x;
        const float* y;
        if (o < 16) { x = hts + r * 256 + (o >> 2) * 64;  y = ash + (o & 3) * 128; }
        else        { x = hts + r * 256 + (o - 16) * 64;  y = ash + (o - 16) * 128 + 64; }
        float s = 0.f;
        #pragma unroll
        for (int ff = 0; ff < 64; ++ff) {
            int f = (ff + (t << 3)) & 63;   // bank stagger
            s += x[f] * y[f];
        }
        if (o < 16) s1[(i0 + r) * 16 + (o >> 2) * 4 + (o & 3)] = s;
        else        s2p[(o - 16) * 512 + i0 + r] = s;
    }
}

// ---------------- K2: attention + aggregate ----------------
// 256 blocks (64 i-tiles x 4 heads) x 512 thr (8 waves). Wave w: softmax row w,
// then aggregates j-chunk [w*64, w*64+64) for ALL 8 rows; LDS cross-wave reduce.
__global__ __launch_bounds__(512) void k_att(
    const int* __restrict__ adj, const float* __restrict__ ew,
    const float* __restrict__ ht, const float* __restrict__ s1,
    const float* __restrict__ s2p, float* __restrict__ c)
{
    __shared__ float att[8 * 512];   // scores -> alpha -> (reused) partial-c
    __shared__ float s1sh[32];
    __shared__ float s2sh[512];
    const int t = threadIdx.x;
    const int hh = blockIdx.x & 3;
    const int i0 = (blockIdx.x >> 2) * 8;

    s2sh[t] = s2p[hh * 512 + t];
    if (t < 32) s1sh[t] = s1[(i0 + (t >> 2)) * 16 + (t & 3) * 4 + hh];
    __syncthreads();

    #pragma unroll
    for (int pass = 0; pass < 8; ++pass) {
        int idx = pass * 512 + t;
        int r = idx >> 9, j = idx & 511;
        float e = s1sh[r * 4 + (j >> 7)] + s2sh[j];
        e = (e >= 0.f) ? e : 0.2f * e;
        e *= ew[(i0 + r) * 512 + j];
        att[idx] = (adj[(i0 + r) * 512 + j] > 0) ? e : -9.0e15f;
    }
    __syncthreads();

    const int w = t >> 6, lane = t & 63;
    {   // softmax of row w (2 LDS passes: exp stored in place)
        float m = -INFINITY;
        #pragma unroll
        for (int k = 0; k < 8; ++k) m = fmaxf(m, att[w * 512 + k * 64 + lane]);
        m = wave_max(m);
        float s = 0.f;
        #pragma unroll
        for (int k = 0; k < 8; ++k) {
            float v = __expf(att[w * 512 + k * 64 + lane] - m);
            s += v;
            att[w * 512 + k * 64 + lane] = v;
        }
        s = wave_sum(s);
        float inv = 1.f / s;
        #pragma unroll
        for (int k = 0; k < 8; ++k) att[w * 512 + k * 64 + lane] *= inv;
    }
    __syncthreads();

    // aggregate: wave w covers j in [w*64, w*64+64) for all 8 rows
    float pacc[8] = {0.f, 0.f, 0.f, 0.f, 0.f, 0.f, 0.f, 0.f};
    const float* htp = ht + hh * 64 + lane;
    const int jbase = w * 64;
    #pragma unroll 4
    for (int jj = 0; jj < 64; jj += 4) {
        const int j = jbase + jj;
        float hv0 = htp[(j + 0) * 256];
        float hv1 = htp[(j + 1) * 256];
        float hv2 = htp[(j + 2) * 256];
        float hv3 = htp[(j + 3) * 256];
        #pragma unroll
        for (int r = 0; r < 8; ++r) {
            float4 ar = *(const float4*)&att[r * 512 + j];  // LDS broadcast
            pacc[r] += ar.x * hv0 + ar.y * hv1 + ar.z * hv2 + ar.w * hv3;
        }
    }
    __syncthreads();
    #pragma unroll
    for (int r = 0; r < 8; ++r) att[w * 512 + r * 64 + lane] = pacc[r];
    __syncthreads();
    float s = 0.f;
    #pragma unroll
    for (int v = 0; v < 8; ++v) s += att[v * 512 + w * 64 + lane];
    c[(i0 + w) * 256 + hh * 64 + lane] = s;
}

// ---------------- K3: out = sigmoid(h U^T + c V^T) ----------------
// 256 blocks x 256 thr, 2 rows/block.
__global__ __launch_bounds__(256) void k_out(
    const float* __restrict__ h, const float* __restrict__ cbuf,
    const float* __restrict__ U, const float* __restrict__ V,
    float* __restrict__ out)
{
    __shared__ float hsh[2 * 128];
    __shared__ float csh[2 * 256];
    const int t = threadIdx.x;
    const int i0 = blockIdx.x * 2;
    if (t < 64)   ((float4*)hsh)[t]       = ((const float4*)(h + i0 * 128))[t];
    if (t >= 128) ((float4*)csh)[t - 128] = ((const float4*)(cbuf + i0 * 256))[t - 128];
    __syncthreads();

    float acc0 = 0.f, acc1 = 0.f;
    const float4* Uv = (const float4*)(U + t * 128);
    #pragma unroll
    for (int kk = 0; kk < 32; ++kk) {
        float4 u4 = Uv[kk];
        const float* h0 = hsh + kk * 4;
        const float* h1 = hsh + 128 + kk * 4;
        acc0 += u4.x * h0[0] + u4.y * h0[1] + u4.z * h0[2] + u4.w * h0[3];
        acc1 += u4.x * h1[0] + u4.y * h1[1] + u4.z * h1[2] + u4.w * h1[3];
    }
    const float4* Vv = (const float4*)(V + t * 256);
    #pragma unroll
    for (int kk = 0; kk < 64; ++kk) {
        float4 v4 = Vv[kk];
        const float* c0 = csh + kk * 4;
        const float* c1 = csh + 256 + kk * 4;
        acc0 += v4.x * c0[0] + v4.y * c0[1] + v4.z * c0[2] + v4.w * c0[3];
        acc1 += v4.x * c1[0] + v4.y * c1[1] + v4.z * c1[2] + v4.w * c1[3];
    }
    out[i0 * 256 + t]       = 1.f / (1.f + __expf(-acc0));
    out[(i0 + 1) * 256 + t] = 1.f / (1.f + __expf(-acc1));
}

extern "C" void kernel_launch(void* const* d_in, const int* in_sizes, int n_in,
                              void* d_out, int out_size, void* d_ws, size_t ws_size,
                              hipStream_t stream) {
    const float* h   = (const float*)d_in[0];
    const int*   adj = (const int*)d_in[1];
    const float* ew  = (const float*)d_in[2];
    const float* W   = (const float*)d_in[3];
    const float* a   = (const float*)d_in[4];
    const float* U   = (const float*)d_in[5];
    const float* V   = (const float*)d_in[6];
    float* out = (float*)d_out;

    float* ht  = (float*)d_ws;           // 512*256
    float* s1  = ht + 512 * 256;         // 512*16
    float* s2p = s1 + 512 * 16;          // 4*512
    float* c   = s2p + 4 * 512;          // 512*256

    k_transform<<<256, 256, 0, stream>>>(h, W, a, ht, s1, s2p);
    k_att<<<256, 512, 0, stream>>>(adj, ew, ht, s1, s2p, c);
    k_out<<<256, 256, 0, stream>>>(h, c, U, V, out);
}